// Round 8
// baseline (3052.386 us; speedup 1.0000x reference)
//
#include <hip/hip_runtime.h>

typedef _Float16 h8 __attribute__((ext_vector_type(8)));
typedef float    f4 __attribute__((ext_vector_type(4)));
typedef unsigned u4 __attribute__((ext_vector_type(4)));

// ---------------- workspace layout (bytes) ----------------
// hbuf32 : 2*8*8*512 fp32 = 262,144  [parity][ig 8][row 8][unit 512]
//          each dword: fp32 h with 10-bit step tag in mantissa LSBs
static const unsigned long long WS_NEEDED = 262144ull;

__device__ __forceinline__ float sigm(float x)   { return 1.0f / (1.0f + __expf(-x)); }
__device__ __forceinline__ float tanh_a(float x) { return 2.0f / (1.0f + __expf(-2.0f * x)) - 1.0f; }

// ---------------- k_init: fill h buffer with tag=1023, value~0 ----------------
__global__ __launch_bounds__(256) void k_init(unsigned* hbuf)
{
    const int idx = blockIdx.x * 256 + threadIdx.x;
    if (idx < 65536) hbuf[idx] = 0x000003FFu;
}

// R15 = drain-free ping-pong. R14 regressed because every spin exit ended
// in VWAIT(0): on the retry path that drain waits ~900cy on the just-
// reissued loser set. Fix: NEVER drain. The loser set stays in flight
// across the step boundary; the next head's VWAIT(4) (issued after
// PROBE_Q) retires it as the oldest outstanding, folded into the same
// wait that retires pub4+xq2. Register safety without a drain:
//  - winning set's regs are read directly (wave-uniform use_r branch),
//    no copy, no read of in-flight regs;
//  - loser set's regs are next WRITTEN by t+1's PROBE of that set, which
//    runs after t+1's head VWAIT(4) has retired the old loads; and VMEM
//    writes land in issue order per wave, so even overlapping WAW
//    resolves to the newest load's data.
// vmcnt ledger (uniform: every wave issues 4 pub stores, exec!=0):
//   head: outstanding = leftover(0..6, oldest) + pub4 + xq2
//         PROBE_Q(4) -> VWAIT(4) retires leftover+pub+xq, leaves P1
//         stage ldsX (xq retired); issue x_{t+2}(2); PROBE_R(4) -> 10
//   spin: VWAIT(6) resolves P1 (leaves x2+R)
//         check Q; miss -> PROBE_Q, VWAIT(4) resolves R (retires x2 too)
//         check R; miss -> PROBE_R, VWAIT(4) resolves Q; repeat
//   exit: NO drain. Winning set -> ldsH; loser rides to next head.
// After the t-loop: one VWAIT(0) before return (clean kernel exit).
// Every waitcnt is followed by sched_barrier(0) (rule 18).

#define VWAIT(N) do { asm volatile("s_waitcnt vmcnt(" #N ")" ::: "memory"); \
                      __builtin_amdgcn_sched_barrier(0); } while (0)
#define LBAR()   do { asm volatile("s_waitcnt lgkmcnt(0)" ::: "memory"); \
                      __builtin_amdgcn_s_barrier(); \
                      __builtin_amdgcn_sched_barrier(0); } while (0)

#define PROBE_Q() \
    asm volatile( \
        "global_load_dwordx4 %0, %4, off sc0 sc1\n\t" \
        "global_load_dwordx4 %1, %4, off offset:16 sc0 sc1\n\t" \
        "global_load_dwordx4 %2, %4, off offset:1024 sc0 sc1\n\t" \
        "global_load_dwordx4 %3, %4, off offset:1040 sc0 sc1" \
        : "=&v"(qa), "=&v"(qb), "=&v"(qc), "=&v"(qd) \
        : "v"(hp) : "memory")
#define PROBE_R() \
    asm volatile( \
        "global_load_dwordx4 %0, %4, off sc0 sc1\n\t" \
        "global_load_dwordx4 %1, %4, off offset:16 sc0 sc1\n\t" \
        "global_load_dwordx4 %2, %4, off offset:1024 sc0 sc1\n\t" \
        "global_load_dwordx4 %3, %4, off offset:1040 sc0 sc1" \
        : "=&v"(ra), "=&v"(rb), "=&v"(rc), "=&v"(rd) \
        : "v"(hp) : "memory")

#define TAGQ() ((qa[0]^etag)|(qa[1]^etag)|(qa[2]^etag)|(qa[3]^etag)| \
                (qb[0]^etag)|(qb[1]^etag)|(qb[2]^etag)|(qb[3]^etag)| \
                (qc[0]^etag)|(qc[1]^etag)|(qc[2]^etag)|(qc[3]^etag)| \
                (qd[0]^etag)|(qd[1]^etag)|(qd[2]^etag)|(qd[3]^etag))
#define TAGR() ((ra[0]^etag)|(ra[1]^etag)|(ra[2]^etag)|(ra[3]^etag)| \
                (rb[0]^etag)|(rb[1]^etag)|(rb[2]^etag)|(rb[3]^etag)| \
                (rc[0]^etag)|(rc[1]^etag)|(rc[2]^etag)|(rc[3]^etag)| \
                (rd[0]^etag)|(rd[1]^etag)|(rd[2]^etag)|(rd[3]^etag))

__device__ __forceinline__ h8 pack8h(u4 a, u4 b)
{
    h8 p;
    p[0] = (_Float16)__uint_as_float(a[0] & 0xFFFFFC00u);
    p[1] = (_Float16)__uint_as_float(a[1] & 0xFFFFFC00u);
    p[2] = (_Float16)__uint_as_float(a[2] & 0xFFFFFC00u);
    p[3] = (_Float16)__uint_as_float(a[3] & 0xFFFFFC00u);
    p[4] = (_Float16)__uint_as_float(b[0] & 0xFFFFFC00u);
    p[5] = (_Float16)__uint_as_float(b[1] & 0xFFFFFC00u);
    p[6] = (_Float16)__uint_as_float(b[2] & 0xFFFFFC00u);
    p[7] = (_Float16)__uint_as_float(b[3] & 0xFFFFFC00u);
    return p;
}
__device__ __forceinline__ h8 pack8f(f4 a, f4 b)
{
    h8 p;
    p[0] = (_Float16)a[0]; p[1] = (_Float16)a[1];
    p[2] = (_Float16)a[2]; p[3] = (_Float16)a[3];
    p[4] = (_Float16)b[0]; p[5] = (_Float16)b[1];
    p[6] = (_Float16)b[2]; p[7] = (_Float16)b[3];
    return p;
}

__global__ __launch_bounds__(256, 1) void k_rec(
    const float* __restrict__ x,
    const float* __restrict__ Ui, const float* __restrict__ Vi, const float* __restrict__ bi,
    const float* __restrict__ Uf, const float* __restrict__ Vf, const float* __restrict__ bf,
    const float* __restrict__ Uh, const float* __restrict__ Vh, const float* __restrict__ bh,
    const float* __restrict__ Uo, const float* __restrict__ Vo, const float* __restrict__ bo,
    unsigned* hbuf)
{
    const int bx = blockIdx.x;
    const int ig = bx & 7;
    const int jg = bx >> 3;
    const int tid = threadIdx.x;
    const int w = tid >> 6, l = tid & 63;
    const int lo = l & 15, hi = l >> 4;
    const int r8 = lo & 7;
    const int unit = jg * 64 + w * 16 + lo;

    // double-buffered (parity = t&1): one barrier per step, race-free
    __shared__ __align__(16) _Float16 ldsH[2][16 * 32 * 8];   // 16 KB
    __shared__ __align__(16) _Float16 ldsX[2][8 * 32 * 8];    //  8 KB

    const float* Ug[4] = {Ui, Uf, Uh, Uo};
    const float* Vg[4] = {Vi, Vf, Vh, Vo};
    const float* bg[4] = {bi, bf, bh, bo};

    // ---- one-time fragment preload (fp32 -> fp16 cvt) ----
    h8 vfrag[4][16];   // V: K=512 -> 16 k-chunks
    h8 ufrag[4][8];    // U: K=256 ->  8 k-chunks
    float bias[4];
#pragma unroll
    for (int g = 0; g < 4; ++g) {
        bias[g] = bg[g][unit];
#pragma unroll
        for (int kc = 0; kc < 16; ++kc) {
            h8 v;
#pragma unroll
            for (int jj = 0; jj < 8; ++jj)
                v[jj] = (_Float16)Vg[g][(size_t)(kc * 32 + hi * 8 + jj) * 512 + unit];
            vfrag[g][kc] = v;
        }
#pragma unroll
        for (int kc = 0; kc < 8; ++kc) {
            h8 u;
#pragma unroll
            for (int jj = 0; jj < 8; ++jj)
                u[jj] = (_Float16)Ug[g][(size_t)(kc * 32 + hi * 8 + jj) * 512 + unit];
            ufrag[g][kc] = u;
        }
    }

    // ---- staging map: thread -> (row sr, 8-unit granule at sc) per half ----
    const int sr = tid >> 5;              // batch row 0..7
    const int sc = (tid & 31) * 8;        // unit base within half (0..248)
    const int kc1 = sc >> 5;              // k-chunk 0..7 (half1); half2 = kc1+8
    const int hg1 = (sc >> 3) & 3;        // hi coord of granule
    const int sw1 = ((kc1 & 1) << 2) | hg1;
    const int g1 = kc1 * 32 + hg1 * 8 + (sr ^ sw1);        // half1 / x granule
    const int g2 = (kc1 + 8) * 32 + hg1 * 8 + (sr ^ sw1);  // half2 granule

    const float* xrb = x + (size_t)(ig * 8 + sr) * 262144 + sc;

    f4 cst = {0.f, 0.f, 0.f, 0.f};
    f4 xq0, xq1;                          // prefetched x_{t+1}

    // ---- prologue: stage x_0 -> ldsX[0]; issue x_1 loads ----
    {
        f4 a0, a1;
        asm volatile("global_load_dwordx4 %0, %2, off\n\t"
                     "global_load_dwordx4 %1, %2, off offset:16"
                     : "=&v"(a0), "=&v"(a1) : "v"(xrb) : "memory");
        VWAIT(0);
        *(h8*)&ldsX[0][(size_t)g1 * 8] = pack8f(a0, a1);
        const float* xp1 = xrb + 256;
        asm volatile("global_load_dwordx4 %0, %2, off\n\t"
                     "global_load_dwordx4 %1, %2, off offset:16"
                     : "=&v"(xq0), "=&v"(xq1) : "v"(xp1) : "memory");
        LBAR();
    }

    for (int t = 0; t < 1024; ++t) {
        const int pb = t & 1, pn = pb ^ 1;
        const int pr = (t + 1) & 1;                         // slab holding h_{t-1}
        const unsigned etag = (unsigned)((t + 1023) & 1023);
        const unsigned* hp = hbuf + (size_t)(pr * 8 + ig) * 4096
                                  + (size_t)sr * 512 + sc;

        // ---- phase A: gates = bias + x_t @ U; dual 4-deep chains.
        //      Runs BEFORE the probes (delays the sample past publish). ----
        f4 acc[4], acq[4];
#pragma unroll
        for (int g = 0; g < 4; ++g) {
            f4 a; a[0] = bias[g]; a[1] = bias[g]; a[2] = bias[g]; a[3] = bias[g];
            acc[g] = a;
            f4 z; z[0] = 0.f; z[1] = 0.f; z[2] = 0.f; z[3] = 0.f;
            acq[g] = z;
        }
#pragma unroll
        for (int k = 0; k < 4; ++k) {
            const int ke = 2 * k, ko = 2 * k + 1;
            const int ga = ke * 32 + hi * 8 + (r8 ^ (((ke & 1) << 2) | hi));
            const int gb = ko * 32 + hi * 8 + (r8 ^ (((ko & 1) << 2) | hi));
            const h8 xa = *(const h8*)&ldsX[pb][(size_t)ga * 8];
            const h8 xb = *(const h8*)&ldsX[pb][(size_t)gb * 8];
            acc[0] = __builtin_amdgcn_mfma_f32_16x16x32_f16(xa, ufrag[0][ke], acc[0], 0, 0, 0);
            acc[1] = __builtin_amdgcn_mfma_f32_16x16x32_f16(xa, ufrag[1][ke], acc[1], 0, 0, 0);
            acc[2] = __builtin_amdgcn_mfma_f32_16x16x32_f16(xa, ufrag[2][ke], acc[2], 0, 0, 0);
            acc[3] = __builtin_amdgcn_mfma_f32_16x16x32_f16(xa, ufrag[3][ke], acc[3], 0, 0, 0);
            acq[0] = __builtin_amdgcn_mfma_f32_16x16x32_f16(xb, ufrag[0][ko], acq[0], 0, 0, 0);
            acq[1] = __builtin_amdgcn_mfma_f32_16x16x32_f16(xb, ufrag[1][ko], acq[1], 0, 0, 0);
            acq[2] = __builtin_amdgcn_mfma_f32_16x16x32_f16(xb, ufrag[2][ko], acq[2], 0, 0, 0);
            acq[3] = __builtin_amdgcn_mfma_f32_16x16x32_f16(xb, ufrag[3][ko], acq[3], 0, 0, 0);
        }

        // ---- head: P1; retire {leftover, pub(t-1), xq}; stage x; x_{t+2}; P2 ----
        u4 qa, qb, qc, qd, ra, rb, rc, rd;
        PROBE_Q();
        VWAIT(4);   // retires leftover set (oldest) + pub4 + xq2; leaves P1
        *(h8*)&ldsX[pn][(size_t)g1 * 8] = pack8f(xq0, xq1);
        {
            const int tn = (t + 2 < 1024) ? t + 2 : 1023;
            const float* xp = xrb + (size_t)tn * 256;
            asm volatile("global_load_dwordx4 %0, %2, off\n\t"
                         "global_load_dwordx4 %1, %2, off offset:16"
                         : "=&v"(xq0), "=&v"(xq1) : "v"(xp) : "memory");
        }
        PROBE_R();   // outstanding: P1(4) + x2 + R(4) = 10

        // ---- drain-free ping-pong spin ----
        int use_r = 0;
        {
            int tries = 0;
            VWAIT(6);                       // resolve P1 (leaves x2 + R)
            for (;;) {
                unsigned m = TAGQ();
                if (__all((m & 1023u) == 0u)) { use_r = 0; break; }
                if (++tries > 8192) { use_r = 0; break; }   // absmax-fail, no hang
                PROBE_Q();
                VWAIT(4);                   // resolve R (retires x2 too); Q in flight
                m = TAGR();
                if (__all((m & 1023u) == 0u)) { use_r = 1; break; }
                if (++tries > 8192) { use_r = 1; break; }
                PROBE_R();
                VWAIT(4);                   // resolve Q; R in flight
            }
        }

        // ---- stage winning set -> ldsH[pb] (loser stays in flight) ----
        if (use_r) {
            *(h8*)&ldsH[pb][(size_t)g1 * 8] = pack8h(ra, rb);
            *(h8*)&ldsH[pb][(size_t)g2 * 8] = pack8h(rc, rd);
        } else {
            *(h8*)&ldsH[pb][(size_t)g1 * 8] = pack8h(qa, qb);
            *(h8*)&ldsH[pb][(size_t)g2 * 8] = pack8h(qc, qd);
        }
        LBAR();   // the ONLY barrier per step

        // ---- phase B: h_{t-1} @ V; dual 8-deep chains (kc k and k+8) ----
#pragma unroll
        for (int k = 0; k < 8; ++k) {
            const int kh = k + 8;
            const int ga = k  * 32 + hi * 8 + (r8 ^ (((k  & 1) << 2) | hi));
            const int gb = kh * 32 + hi * 8 + (r8 ^ (((kh & 1) << 2) | hi));
            const h8 a0 = *(const h8*)&ldsH[pb][(size_t)ga * 8];
            const h8 a1 = *(const h8*)&ldsH[pb][(size_t)gb * 8];
            acc[0] = __builtin_amdgcn_mfma_f32_16x16x32_f16(a0, vfrag[0][k],  acc[0], 0, 0, 0);
            acc[1] = __builtin_amdgcn_mfma_f32_16x16x32_f16(a0, vfrag[1][k],  acc[1], 0, 0, 0);
            acc[2] = __builtin_amdgcn_mfma_f32_16x16x32_f16(a0, vfrag[2][k],  acc[2], 0, 0, 0);
            acc[3] = __builtin_amdgcn_mfma_f32_16x16x32_f16(a0, vfrag[3][k],  acc[3], 0, 0, 0);
            acq[0] = __builtin_amdgcn_mfma_f32_16x16x32_f16(a1, vfrag[0][kh], acq[0], 0, 0, 0);
            acq[1] = __builtin_amdgcn_mfma_f32_16x16x32_f16(a1, vfrag[1][kh], acq[1], 0, 0, 0);
            acq[2] = __builtin_amdgcn_mfma_f32_16x16x32_f16(a1, vfrag[2][kh], acq[2], 0, 0, 0);
            acq[3] = __builtin_amdgcn_mfma_f32_16x16x32_f16(a1, vfrag[3][kh], acq[3], 0, 0, 0);
        }

        // ---- merge chains + elementwise + tagged agent-scope publish ----
        const unsigned ptag = (unsigned)(t & 1023);
        unsigned pub[4];
#pragma unroll
        for (int d = 0; d < 4; ++d) {
            const float iv = sigm(acc[0][d] + acq[0][d]);
            const float fv = sigm(acc[1][d] + acq[1][d]);
            const float gv = tanh_a(acc[2][d] + acq[2][d]);
            const float ov = sigm(acc[3][d] + acq[3][d]);
            const float c = fv * cst[d] + iv * gv;
            cst[d] = c;
            const float hv = ov * tanh_a(c);
            pub[d] = (__float_as_uint(hv) & 0xFFFFFC00u) | ptag;
        }
        if (hi < 2) {
            unsigned* hw = hbuf + (size_t)((pb * 8 + ig) * 8 + hi * 4) * 512 + unit;
            asm volatile(
                "global_store_dword %4, %0, off sc0 sc1\n\t"
                "global_store_dword %4, %1, off offset:2048 sc0 sc1\n\t"
                "global_store_dword %5, %2, off sc0 sc1\n\t"
                "global_store_dword %5, %3, off offset:2048 sc0 sc1"
                :: "v"(pub[0]), "v"(pub[1]), "v"(pub[2]), "v"(pub[3]),
                   "v"(hw), "v"(hw + 1024)
                : "memory");
        }
    }

    VWAIT(0);   // clean exit: retire any loads still in flight
}

// ---------------- k_fc: out[b] = h_last[b,:] . fc_w + fc_b ----------------
__global__ __launch_bounds__(64) void k_fc(
    const unsigned* __restrict__ hbuf, const float* __restrict__ fcw,
    const float* __restrict__ fcb, float* __restrict__ out)
{
    const int b = blockIdx.x, l = threadIdx.x;
    // h_1023 lives at parity 1; ig = b>>3, row = b&7; mask the tag bits
    const unsigned* h = hbuf + (size_t)((8 + (b >> 3)) * 8 + (b & 7)) * 512;
    float s = 0.f;
#pragma unroll
    for (int k = 0; k < 8; ++k) {
        const float hv = __uint_as_float(h[l + k * 64] & 0xFFFFFC00u);
        s += hv * fcw[l + k * 64];
    }
    for (int off = 32; off > 0; off >>= 1) s += __shfl_down(s, off, 64);
    if (l == 0) out[b] = s + fcb[0];
}

__global__ __launch_bounds__(64) void k_sentinel(float* out)
{
    out[threadIdx.x] = -777777.0f;   // signature: ws_size too small
}

extern "C" void kernel_launch(void* const* d_in, const int* in_sizes, int n_in,
                              void* d_out, int out_size, void* d_ws, size_t ws_size,
                              hipStream_t stream)
{
    const float* x   = (const float*)d_in[0];
    const float* Ui  = (const float*)d_in[1];
    const float* Vi  = (const float*)d_in[2];
    const float* bi  = (const float*)d_in[3];
    const float* Uf  = (const float*)d_in[4];
    const float* Vf  = (const float*)d_in[5];
    const float* bf  = (const float*)d_in[6];
    const float* Uh  = (const float*)d_in[7];
    const float* Vh  = (const float*)d_in[8];
    const float* bh  = (const float*)d_in[9];
    const float* Uo  = (const float*)d_in[10];
    const float* Vo  = (const float*)d_in[11];
    const float* bo  = (const float*)d_in[12];
    const float* fcw = (const float*)d_in[13];
    const float* fcb = (const float*)d_in[14];
    float* out = (float*)d_out;

    if (ws_size < WS_NEEDED) {
        k_sentinel<<<1, 64, 0, stream>>>(out);
        return;
    }

    unsigned* hbuf = (unsigned*)d_ws;

    k_init<<<256, 256, 0, stream>>>(hbuf);
    k_rec <<<64,  256, 0, stream>>>(x, Ui, Vi, bi, Uf, Vf, bf, Uh, Vh, bh,
                                    Uo, Vo, bo, hbuf);
    k_fc  <<<64,   64, 0, stream>>>(hbuf, fcw, fcb, out);
}

// Round 10
// 2707.286 us; speedup vs baseline: 1.1275x; 1.1275x over previous
//
#include <hip/hip_runtime.h>

typedef _Float16 h8 __attribute__((ext_vector_type(8)));
typedef float    f4 __attribute__((ext_vector_type(4)));
typedef unsigned u4 __attribute__((ext_vector_type(4)));

// ---------------- workspace layout (bytes) ----------------
// hbuf32 : 2*8*8*512 fp32 = 262,144  [parity][ig 8][row 8][unit 512]
//          each dword: fp32 h with 10-bit step tag in mantissa LSBs
static const unsigned long long WS_NEEDED = 262144ull;

__device__ __forceinline__ float sigm(float x)   { return 1.0f / (1.0f + __expf(-x)); }
__device__ __forceinline__ float tanh_a(float x) { return 2.0f / (1.0f + __expf(-2.0f * x)) - 1.0f; }

// ---------------- k_init: fill h buffer with tag=1023, value~0 ----------------
__global__ __launch_bounds__(256) void k_init(unsigned* hbuf)
{
    const int idx = blockIdx.x * 256 + threadIdx.x;
    if (idx < 65536) hbuf[idx] = 0x000003FFu;
}

// R17 = R11 (verified 2682us) + DIVERGENT PER-LANE SPIN.
// Post-mortem of the R12-R16 arc: every scheme keeping probe loads in
// flight across structural boundaries broke correctness (R10/R13/R16) or
// re-paid the latency elsewhere (R14/R15). R11's residual ~3800cy/step
// spin despite a ~1400cy uncongested round trip points at SELF-INFLICTED
// MALL CONGESTION: ~1.2 TB/s of scattered 64B probe traffic (8 blocks x
// 16KB x retries x 8 teams / 2.6us) inflating visibility + RT.
// Fix: each lane's 4 probe loads cover exactly ONE producer block, so the
// spin exit becomes per-lane (no __all). Lanes that pass drop out of the
// divergent loop and stop issuing loads (exec-masked VMEM preserves their
// registers); only lanes watching the slow producer keep probing -> ~8x
// less retry traffic. Ledger invariant unchanged: every pass begins with
// VWAIT(0); the last lane exits post-wait pre-probe, so the wave leaves
// the spin fully drained, exactly like R11.
// Every waitcnt is followed by sched_barrier(0) (rule 18).

#define VWAIT0() do { asm volatile("s_waitcnt vmcnt(0)" ::: "memory"); \
                      __builtin_amdgcn_sched_barrier(0); } while (0)
#define LBAR()   do { asm volatile("s_waitcnt lgkmcnt(0)" ::: "memory"); \
                      __builtin_amdgcn_s_barrier(); \
                      __builtin_amdgcn_sched_barrier(0); } while (0)

#define PROBE4() \
    asm volatile( \
        "global_load_dwordx4 %0, %4, off sc0 sc1\n\t" \
        "global_load_dwordx4 %1, %4, off offset:16 sc0 sc1\n\t" \
        "global_load_dwordx4 %2, %4, off offset:1024 sc0 sc1\n\t" \
        "global_load_dwordx4 %3, %4, off offset:1040 sc0 sc1" \
        : "=&v"(qa), "=&v"(qb), "=&v"(qc), "=&v"(qd) \
        : "v"(hp) : "memory")

__device__ __forceinline__ h8 pack8h(u4 a, u4 b)
{
    h8 p;
    p[0] = (_Float16)__uint_as_float(a[0] & 0xFFFFFC00u);
    p[1] = (_Float16)__uint_as_float(a[1] & 0xFFFFFC00u);
    p[2] = (_Float16)__uint_as_float(a[2] & 0xFFFFFC00u);
    p[3] = (_Float16)__uint_as_float(a[3] & 0xFFFFFC00u);
    p[4] = (_Float16)__uint_as_float(b[0] & 0xFFFFFC00u);
    p[5] = (_Float16)__uint_as_float(b[1] & 0xFFFFFC00u);
    p[6] = (_Float16)__uint_as_float(b[2] & 0xFFFFFC00u);
    p[7] = (_Float16)__uint_as_float(b[3] & 0xFFFFFC00u);
    return p;
}
__device__ __forceinline__ h8 pack8f(f4 a, f4 b)
{
    h8 p;
    p[0] = (_Float16)a[0]; p[1] = (_Float16)a[1];
    p[2] = (_Float16)a[2]; p[3] = (_Float16)a[3];
    p[4] = (_Float16)b[0]; p[5] = (_Float16)b[1];
    p[6] = (_Float16)b[2]; p[7] = (_Float16)b[3];
    return p;
}

__global__ __launch_bounds__(256, 1) void k_rec(
    const float* __restrict__ x,
    const float* __restrict__ Ui, const float* __restrict__ Vi, const float* __restrict__ bi,
    const float* __restrict__ Uf, const float* __restrict__ Vf, const float* __restrict__ bf,
    const float* __restrict__ Uh, const float* __restrict__ Vh, const float* __restrict__ bh,
    const float* __restrict__ Uo, const float* __restrict__ Vo, const float* __restrict__ bo,
    unsigned* hbuf)
{
    const int bx = blockIdx.x;
    const int ig = bx & 7;
    const int jg = bx >> 3;
    const int tid = threadIdx.x;
    const int w = tid >> 6, l = tid & 63;
    const int lo = l & 15, hi = l >> 4;
    const int r8 = lo & 7;
    const int unit = jg * 64 + w * 16 + lo;

    // double-buffered (parity = t&1): one barrier per step, race-free
    __shared__ __align__(16) _Float16 ldsH[2][16 * 32 * 8];   // 16 KB
    __shared__ __align__(16) _Float16 ldsX[2][8 * 32 * 8];    //  8 KB

    const float* Ug[4] = {Ui, Uf, Uh, Uo};
    const float* Vg[4] = {Vi, Vf, Vh, Vo};
    const float* bg[4] = {bi, bf, bh, bo};

    // ---- one-time fragment preload (fp32 -> fp16 cvt) ----
    h8 vfrag[4][16];   // V: K=512 -> 16 k-chunks
    h8 ufrag[4][8];    // U: K=256 ->  8 k-chunks
    float bias[4];
#pragma unroll
    for (int g = 0; g < 4; ++g) {
        bias[g] = bg[g][unit];
#pragma unroll
        for (int kc = 0; kc < 16; ++kc) {
            h8 v;
#pragma unroll
            for (int jj = 0; jj < 8; ++jj)
                v[jj] = (_Float16)Vg[g][(size_t)(kc * 32 + hi * 8 + jj) * 512 + unit];
            vfrag[g][kc] = v;
        }
#pragma unroll
        for (int kc = 0; kc < 8; ++kc) {
            h8 u;
#pragma unroll
            for (int jj = 0; jj < 8; ++jj)
                u[jj] = (_Float16)Ug[g][(size_t)(kc * 32 + hi * 8 + jj) * 512 + unit];
            ufrag[g][kc] = u;
        }
    }

    // ---- staging map: thread -> (row sr, 8-unit granule at sc) per half ----
    const int sr = tid >> 5;              // batch row 0..7
    const int sc = (tid & 31) * 8;        // unit base within half (0..248)
    const int kc1 = sc >> 5;              // k-chunk 0..7 (half1); half2 = kc1+8
    const int hg1 = (sc >> 3) & 3;        // hi coord of granule
    const int sw1 = ((kc1 & 1) << 2) | hg1;
    const int g1 = kc1 * 32 + hg1 * 8 + (sr ^ sw1);        // half1 / x granule
    const int g2 = (kc1 + 8) * 32 + hg1 * 8 + (sr ^ sw1);  // half2 granule

    const float* xrb = x + (size_t)(ig * 8 + sr) * 262144 + sc;

    f4 cst = {0.f, 0.f, 0.f, 0.f};
    f4 xq0, xq1;                          // prefetched x_{t+1}

    // ---- prologue: stage x_0 -> ldsX[0]; issue x_1 loads ----
    {
        f4 a0, a1;
        asm volatile("global_load_dwordx4 %0, %2, off\n\t"
                     "global_load_dwordx4 %1, %2, off offset:16"
                     : "=&v"(a0), "=&v"(a1) : "v"(xrb) : "memory");
        VWAIT0();
        *(h8*)&ldsX[0][(size_t)g1 * 8] = pack8f(a0, a1);
        const float* xp1 = xrb + 256;
        asm volatile("global_load_dwordx4 %0, %2, off\n\t"
                     "global_load_dwordx4 %1, %2, off offset:16"
                     : "=&v"(xq0), "=&v"(xq1) : "v"(xp1) : "memory");
        LBAR();
    }

    for (int t = 0; t < 1024; ++t) {
        const int pb = t & 1, pn = pb ^ 1;
        const int pr = (t + 1) & 1;                         // slab holding h_{t-1}
        const unsigned etag = (unsigned)((t + 1023) & 1023);
        const unsigned* hp = hbuf + (size_t)(pr * 8 + ig) * 4096
                                  + (size_t)sr * 512 + sc;

        // ---- phase A: gates = bias + x_t @ U; dual 4-deep chains.
        //      Runs BEFORE the probes (delays the sample past publish). ----
        f4 acc[4], acq[4];
#pragma unroll
        for (int g = 0; g < 4; ++g) {
            f4 a; a[0] = bias[g]; a[1] = bias[g]; a[2] = bias[g]; a[3] = bias[g];
            acc[g] = a;
            f4 z; z[0] = 0.f; z[1] = 0.f; z[2] = 0.f; z[3] = 0.f;
            acq[g] = z;
        }
#pragma unroll
        for (int k = 0; k < 4; ++k) {
            const int ke = 2 * k, ko = 2 * k + 1;
            const int ga = ke * 32 + hi * 8 + (r8 ^ (((ke & 1) << 2) | hi));
            const int gb = ko * 32 + hi * 8 + (r8 ^ (((ko & 1) << 2) | hi));
            const h8 xa = *(const h8*)&ldsX[pb][(size_t)ga * 8];
            const h8 xb = *(const h8*)&ldsX[pb][(size_t)gb * 8];
            acc[0] = __builtin_amdgcn_mfma_f32_16x16x32_f16(xa, ufrag[0][ke], acc[0], 0, 0, 0);
            acc[1] = __builtin_amdgcn_mfma_f32_16x16x32_f16(xa, ufrag[1][ke], acc[1], 0, 0, 0);
            acc[2] = __builtin_amdgcn_mfma_f32_16x16x32_f16(xa, ufrag[2][ke], acc[2], 0, 0, 0);
            acc[3] = __builtin_amdgcn_mfma_f32_16x16x32_f16(xa, ufrag[3][ke], acc[3], 0, 0, 0);
            acq[0] = __builtin_amdgcn_mfma_f32_16x16x32_f16(xb, ufrag[0][ko], acq[0], 0, 0, 0);
            acq[1] = __builtin_amdgcn_mfma_f32_16x16x32_f16(xb, ufrag[1][ko], acq[1], 0, 0, 0);
            acq[2] = __builtin_amdgcn_mfma_f32_16x16x32_f16(xb, ufrag[2][ko], acq[2], 0, 0, 0);
            acq[3] = __builtin_amdgcn_mfma_f32_16x16x32_f16(xb, ufrag[3][ko], acq[3], 0, 0, 0);
        }

        // ---- issue all 4 h probes (deliberately after phase A) ----
        u4 qa, qb, qc, qd;
        PROBE4();

        // ---- DIVERGENT spin: per-lane exit. First VWAIT0 retires prev
        //      publishes, the x-prefetch pair (xq safe), and the probes.
        //      Passed lanes drop out and stop issuing loads; only lanes
        //      watching the slow producer keep probing. Wave leaves the
        //      loop post-wait, pre-probe -> fully drained (R11 invariant).
        {
            int tries = 0;
            for (;;) {
                VWAIT0();
                const unsigned m =
                    (qa[0]^etag)|(qa[1]^etag)|(qa[2]^etag)|(qa[3]^etag)|
                    (qb[0]^etag)|(qb[1]^etag)|(qb[2]^etag)|(qb[3]^etag)|
                    (qc[0]^etag)|(qc[1]^etag)|(qc[2]^etag)|(qc[3]^etag)|
                    (qd[0]^etag)|(qd[1]^etag)|(qd[2]^etag)|(qd[3]^etag);
                if ((m & 1023u) == 0u) break;        // per-lane exit
                if (++tries > 8192) break;           // fails absmax, never hangs
                PROBE4();                            // active lanes only
            }
        }

        // ---- stage x_{t+1} (xq retired) + both h halves ----
        *(h8*)&ldsX[pn][(size_t)g1 * 8] = pack8f(xq0, xq1);
        *(h8*)&ldsH[pb][(size_t)g1 * 8] = pack8h(qa, qb);
        *(h8*)&ldsH[pb][(size_t)g2 * 8] = pack8h(qc, qd);

        // ---- issue x_{t+2} loads (retired by next step's spin VWAIT0) ----
        {
            const int tn = (t + 2 < 1024) ? t + 2 : 1023;
            const float* xp = xrb + (size_t)tn * 256;
            asm volatile("global_load_dwordx4 %0, %2, off\n\t"
                         "global_load_dwordx4 %1, %2, off offset:16"
                         : "=&v"(xq0), "=&v"(xq1) : "v"(xp) : "memory");
        }

        LBAR();   // the ONLY barrier per step

        // ---- phase B: h_{t-1} @ V; dual 8-deep chains (kc k and k+8) ----
#pragma unroll
        for (int k = 0; k < 8; ++k) {
            const int kh = k + 8;
            const int ga = k  * 32 + hi * 8 + (r8 ^ (((k  & 1) << 2) | hi));
            const int gb = kh * 32 + hi * 8 + (r8 ^ (((kh & 1) << 2) | hi));
            const h8 a0 = *(const h8*)&ldsH[pb][(size_t)ga * 8];
            const h8 a1 = *(const h8*)&ldsH[pb][(size_t)gb * 8];
            acc[0] = __builtin_amdgcn_mfma_f32_16x16x32_f16(a0, vfrag[0][k],  acc[0], 0, 0, 0);
            acc[1] = __builtin_amdgcn_mfma_f32_16x16x32_f16(a0, vfrag[1][k],  acc[1], 0, 0, 0);
            acc[2] = __builtin_amdgcn_mfma_f32_16x16x32_f16(a0, vfrag[2][k],  acc[2], 0, 0, 0);
            acc[3] = __builtin_amdgcn_mfma_f32_16x16x32_f16(a0, vfrag[3][k],  acc[3], 0, 0, 0);
            acq[0] = __builtin_amdgcn_mfma_f32_16x16x32_f16(a1, vfrag[0][kh], acq[0], 0, 0, 0);
            acq[1] = __builtin_amdgcn_mfma_f32_16x16x32_f16(a1, vfrag[1][kh], acq[1], 0, 0, 0);
            acq[2] = __builtin_amdgcn_mfma_f32_16x16x32_f16(a1, vfrag[2][kh], acq[2], 0, 0, 0);
            acq[3] = __builtin_amdgcn_mfma_f32_16x16x32_f16(a1, vfrag[3][kh], acq[3], 0, 0, 0);
        }

        // ---- merge chains + elementwise + tagged agent-scope publish ----
        const unsigned ptag = (unsigned)(t & 1023);
        unsigned pub[4];
#pragma unroll
        for (int d = 0; d < 4; ++d) {
            const float iv = sigm(acc[0][d] + acq[0][d]);
            const float fv = sigm(acc[1][d] + acq[1][d]);
            const float gv = tanh_a(acc[2][d] + acq[2][d]);
            const float ov = sigm(acc[3][d] + acq[3][d]);
            const float c = fv * cst[d] + iv * gv;
            cst[d] = c;
            const float hv = ov * tanh_a(c);
            pub[d] = (__float_as_uint(hv) & 0xFFFFFC00u) | ptag;
        }
        if (hi < 2) {
            unsigned* hw = hbuf + (size_t)((pb * 8 + ig) * 8 + hi * 4) * 512 + unit;
            asm volatile(
                "global_store_dword %4, %0, off sc0 sc1\n\t"
                "global_store_dword %4, %1, off offset:2048 sc0 sc1\n\t"
                "global_store_dword %5, %2, off sc0 sc1\n\t"
                "global_store_dword %5, %3, off offset:2048 sc0 sc1"
                :: "v"(pub[0]), "v"(pub[1]), "v"(pub[2]), "v"(pub[3]),
                   "v"(hw), "v"(hw + 1024)
                : "memory");
        }
    }
}

// ---------------- k_fc: out[b] = h_last[b,:] . fc_w + fc_b ----------------
__global__ __launch_bounds__(64) void k_fc(
    const unsigned* __restrict__ hbuf, const float* __restrict__ fcw,
    const float* __restrict__ fcb, float* __restrict__ out)
{
    const int b = blockIdx.x, l = threadIdx.x;
    // h_1023 lives at parity 1; ig = b>>3, row = b&7; mask the tag bits
    const unsigned* h = hbuf + (size_t)((8 + (b >> 3)) * 8 + (b & 7)) * 512;
    float s = 0.f;
#pragma unroll
    for (int k = 0; k < 8; ++k) {
        const float hv = __uint_as_float(h[l + k * 64] & 0xFFFFFC00u);
        s += hv * fcw[l + k * 64];
    }
    for (int off = 32; off > 0; off >>= 1) s += __shfl_down(s, off, 64);
    if (l == 0) out[b] = s + fcb[0];
}

__global__ __launch_bounds__(64) void k_sentinel(float* out)
{
    out[threadIdx.x] = -777777.0f;   // signature: ws_size too small
}

extern "C" void kernel_launch(void* const* d_in, const int* in_sizes, int n_in,
                              void* d_out, int out_size, void* d_ws, size_t ws_size,
                              hipStream_t stream)
{
    const float* x   = (const float*)d_in[0];
    const float* Ui  = (const float*)d_in[1];
    const float* Vi  = (const float*)d_in[2];
    const float* bi  = (const float*)d_in[3];
    const float* Uf  = (const float*)d_in[4];
    const float* Vf  = (const float*)d_in[5];
    const float* bf  = (const float*)d_in[6];
    const float* Uh  = (const float*)d_in[7];
    const float* Vh  = (const float*)d_in[8];
    const float* bh  = (const float*)d_in[9];
    const float* Uo  = (const float*)d_in[10];
    const float* Vo  = (const float*)d_in[11];
    const float* bo  = (const float*)d_in[12];
    const float* fcw = (const float*)d_in[13];
    const float* fcb = (const float*)d_in[14];
    float* out = (float*)d_out;

    if (ws_size < WS_NEEDED) {
        k_sentinel<<<1, 64, 0, stream>>>(out);
        return;
    }

    unsigned* hbuf = (unsigned*)d_ws;

    k_init<<<256, 256, 0, stream>>>(hbuf);
    k_rec <<<64,  256, 0, stream>>>(x, Ui, Vi, bi, Uf, Vf, bf, Uh, Vh, bh,
                                    Uo, Vo, bo, hbuf);
    k_fc  <<<64,   64, 0, stream>>>(hbuf, fcw, fcb, out);
}

// Round 11
// 2379.126 us; speedup vs baseline: 1.2830x; 1.1379x over previous
//
#include <hip/hip_runtime.h>

typedef _Float16 h8 __attribute__((ext_vector_type(8)));
typedef float    f4 __attribute__((ext_vector_type(4)));
typedef unsigned u4 __attribute__((ext_vector_type(4)));

// ---------------- workspace layout (bytes) ----------------
// hbuf32 : 2*8*8*512 fp32 = 262,144  [parity][ig 8][row 8][unit 512]
//          each dword: fp32 h with 10-bit step tag in mantissa LSBs
static const unsigned long long WS_NEEDED = 262144ull;

__device__ __forceinline__ float sigm(float x)   { return 1.0f / (1.0f + __expf(-x)); }
__device__ __forceinline__ float tanh_a(float x) { return 2.0f / (1.0f + __expf(-2.0f * x)) - 1.0f; }

// ---------------- k_init: fill h buffer with tag=1023, value~0 ----------------
__global__ __launch_bounds__(256) void k_init(unsigned* hbuf)
{
    const int idx = blockIdx.x * 256 + threadIdx.x;
    if (idx < 65536) hbuf[idx] = 0x000003FFu;
}

// R18 = R17 protocol (verbatim) + K-SPLIT COMPUTE over 128 blocks.
// R17 proved the exchange is at its structural floor (~3400cy/step); the
// remaining lever is the per-wave serial compute chain: each wave summed
// ALL 16 V k-chunks (96 MFMAs ~1860cy issue) regardless of unit split.
// New geometry: 128 blocks x 256 thr; block = 32 units (jg=bx>>3, 0..15);
// waves pair as (ug=w>>1 unit-group, khalf=w&1 K-half). khalf0: U kc0-3,
// V kc0-7; khalf1: the rest. Per-wave MFMA 96 -> 48. Partial gate sums
// meet via a 16KB LDS exchange (lane-contiguous b128, conflict-free, one
// extra barrier). Elementwise/publish split by d: khalf0 owns d{0,1}
// (rows hi*4+0,1), khalf1 d{2,3}; cell state split cst2[2] per wave.
// Staging map, PROBE4, divergent VWAIT0-only spin, publish tags, barrier
// discipline: UNCHANGED from R17 (the bug-prone protocol is untouched;
// compute-map errors fail loudly via absmax).
// Every waitcnt is followed by sched_barrier(0) (rule 18).

#define VWAIT0() do { asm volatile("s_waitcnt vmcnt(0)" ::: "memory"); \
                      __builtin_amdgcn_sched_barrier(0); } while (0)
#define LBAR()   do { asm volatile("s_waitcnt lgkmcnt(0)" ::: "memory"); \
                      __builtin_amdgcn_s_barrier(); \
                      __builtin_amdgcn_sched_barrier(0); } while (0)

#define PROBE4() \
    asm volatile( \
        "global_load_dwordx4 %0, %4, off sc0 sc1\n\t" \
        "global_load_dwordx4 %1, %4, off offset:16 sc0 sc1\n\t" \
        "global_load_dwordx4 %2, %4, off offset:1024 sc0 sc1\n\t" \
        "global_load_dwordx4 %3, %4, off offset:1040 sc0 sc1" \
        : "=&v"(qa), "=&v"(qb), "=&v"(qc), "=&v"(qd) \
        : "v"(hp) : "memory")

__device__ __forceinline__ h8 pack8h(u4 a, u4 b)
{
    h8 p;
    p[0] = (_Float16)__uint_as_float(a[0] & 0xFFFFFC00u);
    p[1] = (_Float16)__uint_as_float(a[1] & 0xFFFFFC00u);
    p[2] = (_Float16)__uint_as_float(a[2] & 0xFFFFFC00u);
    p[3] = (_Float16)__uint_as_float(a[3] & 0xFFFFFC00u);
    p[4] = (_Float16)__uint_as_float(b[0] & 0xFFFFFC00u);
    p[5] = (_Float16)__uint_as_float(b[1] & 0xFFFFFC00u);
    p[6] = (_Float16)__uint_as_float(b[2] & 0xFFFFFC00u);
    p[7] = (_Float16)__uint_as_float(b[3] & 0xFFFFFC00u);
    return p;
}
__device__ __forceinline__ h8 pack8f(f4 a, f4 b)
{
    h8 p;
    p[0] = (_Float16)a[0]; p[1] = (_Float16)a[1];
    p[2] = (_Float16)a[2]; p[3] = (_Float16)a[3];
    p[4] = (_Float16)b[0]; p[5] = (_Float16)b[1];
    p[6] = (_Float16)b[2]; p[7] = (_Float16)b[3];
    return p;
}

__global__ __launch_bounds__(256, 1) void k_rec(
    const float* __restrict__ x,
    const float* __restrict__ Ui, const float* __restrict__ Vi, const float* __restrict__ bi,
    const float* __restrict__ Uf, const float* __restrict__ Vf, const float* __restrict__ bf,
    const float* __restrict__ Uh, const float* __restrict__ Vh, const float* __restrict__ bh,
    const float* __restrict__ Uo, const float* __restrict__ Vo, const float* __restrict__ bo,
    unsigned* hbuf)
{
    const int bx = blockIdx.x;
    const int ig = bx & 7;
    const int jg = bx >> 3;               // 0..15: 32-unit slice
    const int tid = threadIdx.x;
    const int w = tid >> 6, l = tid & 63;
    const int lo = l & 15, hi = l >> 4;
    const int r8 = lo & 7;
    const int ug = w >> 1;                // unit-group within block (0..1)
    const int khalf = w & 1;              // K-half this wave computes
    const int unit = jg * 32 + ug * 16 + lo;

    // double-buffered h/x (parity = t&1) + K-reduction exchange buffer
    __shared__ __align__(16) _Float16 ldsH[2][16 * 32 * 8];   // 16 KB
    __shared__ __align__(16) _Float16 ldsX[2][8 * 32 * 8];    //  8 KB
    __shared__ __align__(16) f4 ldsP[8 * 128];                // 16 KB

    const float* Ug[4] = {Ui, Uf, Uh, Uo};
    const float* Vg[4] = {Vi, Vf, Vh, Vo};
    const float* bg[4] = {bi, bf, bh, bo};

    // ---- one-time fragment preload: this wave's K-half only ----
    h8 vfrag[4][8];    // V: kc = khalf*8 + kk
    h8 ufrag[4][4];    // U: kc = khalf*4 + kk
    float bias[4];
#pragma unroll
    for (int g = 0; g < 4; ++g) {
        bias[g] = (khalf == 0) ? bg[g][unit] : 0.0f;
#pragma unroll
        for (int kk = 0; kk < 8; ++kk) {
            const int kc = khalf * 8 + kk;
            h8 v;
#pragma unroll
            for (int jj = 0; jj < 8; ++jj)
                v[jj] = (_Float16)Vg[g][(size_t)(kc * 32 + hi * 8 + jj) * 512 + unit];
            vfrag[g][kk] = v;
        }
#pragma unroll
        for (int kk = 0; kk < 4; ++kk) {
            const int kc = khalf * 4 + kk;
            h8 u;
#pragma unroll
            for (int jj = 0; jj < 8; ++jj)
                u[jj] = (_Float16)Ug[g][(size_t)(kc * 32 + hi * 8 + jj) * 512 + unit];
            ufrag[g][kk] = u;
        }
    }

    // ---- staging map (VERBATIM R17): thread -> (row sr, granule sc) ----
    const int sr = tid >> 5;              // batch row 0..7
    const int sc = (tid & 31) * 8;        // unit base within half (0..248)
    const int kc1 = sc >> 5;
    const int hg1 = (sc >> 3) & 3;
    const int sw1 = ((kc1 & 1) << 2) | hg1;
    const int g1 = kc1 * 32 + hg1 * 8 + (sr ^ sw1);
    const int g2 = (kc1 + 8) * 32 + hg1 * 8 + (sr ^ sw1);

    const float* xrb = x + (size_t)(ig * 8 + sr) * 262144 + sc;

    float cst2[2] = {0.f, 0.f};           // this wave's 2 cell-state rows
    f4 xq0, xq1;                          // prefetched x_{t+1}

    // ---- prologue (verbatim R17) ----
    {
        f4 a0, a1;
        asm volatile("global_load_dwordx4 %0, %2, off\n\t"
                     "global_load_dwordx4 %1, %2, off offset:16"
                     : "=&v"(a0), "=&v"(a1) : "v"(xrb) : "memory");
        VWAIT0();
        *(h8*)&ldsX[0][(size_t)g1 * 8] = pack8f(a0, a1);
        const float* xp1 = xrb + 256;
        asm volatile("global_load_dwordx4 %0, %2, off\n\t"
                     "global_load_dwordx4 %1, %2, off offset:16"
                     : "=&v"(xq0), "=&v"(xq1) : "v"(xp1) : "memory");
        LBAR();
    }

    for (int t = 0; t < 1024; ++t) {
        const int pb = t & 1, pn = pb ^ 1;
        const int pr = (t + 1) & 1;
        const unsigned etag = (unsigned)((t + 1023) & 1023);
        const unsigned* hp = hbuf + (size_t)(pr * 8 + ig) * 4096
                                  + (size_t)sr * 512 + sc;

        // ---- phase A (K-half): bias + x_t @ U[kc kbA..kbA+3] ----
        f4 acc[4], acq[4];
#pragma unroll
        for (int g = 0; g < 4; ++g) {
            f4 a; a[0] = bias[g]; a[1] = bias[g]; a[2] = bias[g]; a[3] = bias[g];
            acc[g] = a;
            f4 z; z[0] = 0.f; z[1] = 0.f; z[2] = 0.f; z[3] = 0.f;
            acq[g] = z;
        }
        const int kbA = khalf * 4;
#pragma unroll
        for (int kk = 0; kk < 2; ++kk) {
            const int ke = kbA + kk, ko = kbA + 2 + kk;
            const int ga = ke * 32 + hi * 8 + (r8 ^ (((ke & 1) << 2) | hi));
            const int gb = ko * 32 + hi * 8 + (r8 ^ (((ko & 1) << 2) | hi));
            const h8 xa = *(const h8*)&ldsX[pb][(size_t)ga * 8];
            const h8 xb = *(const h8*)&ldsX[pb][(size_t)gb * 8];
            acc[0] = __builtin_amdgcn_mfma_f32_16x16x32_f16(xa, ufrag[0][kk],     acc[0], 0, 0, 0);
            acc[1] = __builtin_amdgcn_mfma_f32_16x16x32_f16(xa, ufrag[1][kk],     acc[1], 0, 0, 0);
            acc[2] = __builtin_amdgcn_mfma_f32_16x16x32_f16(xa, ufrag[2][kk],     acc[2], 0, 0, 0);
            acc[3] = __builtin_amdgcn_mfma_f32_16x16x32_f16(xa, ufrag[3][kk],     acc[3], 0, 0, 0);
            acq[0] = __builtin_amdgcn_mfma_f32_16x16x32_f16(xb, ufrag[0][2 + kk], acq[0], 0, 0, 0);
            acq[1] = __builtin_amdgcn_mfma_f32_16x16x32_f16(xb, ufrag[1][2 + kk], acq[1], 0, 0, 0);
            acq[2] = __builtin_amdgcn_mfma_f32_16x16x32_f16(xb, ufrag[2][2 + kk], acq[2], 0, 0, 0);
            acq[3] = __builtin_amdgcn_mfma_f32_16x16x32_f16(xb, ufrag[3][2 + kk], acq[3], 0, 0, 0);
        }

        // ---- probes + divergent spin (VERBATIM R17) ----
        u4 qa, qb, qc, qd;
        PROBE4();
        {
            int tries = 0;
            for (;;) {
                VWAIT0();
                const unsigned m =
                    (qa[0]^etag)|(qa[1]^etag)|(qa[2]^etag)|(qa[3]^etag)|
                    (qb[0]^etag)|(qb[1]^etag)|(qb[2]^etag)|(qb[3]^etag)|
                    (qc[0]^etag)|(qc[1]^etag)|(qc[2]^etag)|(qc[3]^etag)|
                    (qd[0]^etag)|(qd[1]^etag)|(qd[2]^etag)|(qd[3]^etag);
                if ((m & 1023u) == 0u) break;
                if (++tries > 8192) break;
                PROBE4();
            }
        }

        // ---- stage x_{t+1} + both h halves; issue x_{t+2} (verbatim) ----
        *(h8*)&ldsX[pn][(size_t)g1 * 8] = pack8f(xq0, xq1);
        *(h8*)&ldsH[pb][(size_t)g1 * 8] = pack8h(qa, qb);
        *(h8*)&ldsH[pb][(size_t)g2 * 8] = pack8h(qc, qd);
        {
            const int tn = (t + 2 < 1024) ? t + 2 : 1023;
            const float* xp = xrb + (size_t)tn * 256;
            asm volatile("global_load_dwordx4 %0, %2, off\n\t"
                         "global_load_dwordx4 %1, %2, off offset:16"
                         : "=&v"(xq0), "=&v"(xq1) : "v"(xp) : "memory");
        }

        LBAR();   // staging barrier

        // ---- phase B (K-half): h_{t-1} @ V[kc kbB..kbB+7] ----
        const int kbB = khalf * 8;
#pragma unroll
        for (int kk = 0; kk < 4; ++kk) {
            const int ke = kbB + kk, ko = kbB + 4 + kk;
            const int ga = ke * 32 + hi * 8 + (r8 ^ (((ke & 1) << 2) | hi));
            const int gb = ko * 32 + hi * 8 + (r8 ^ (((ko & 1) << 2) | hi));
            const h8 a0 = *(const h8*)&ldsH[pb][(size_t)ga * 8];
            const h8 a1 = *(const h8*)&ldsH[pb][(size_t)gb * 8];
            acc[0] = __builtin_amdgcn_mfma_f32_16x16x32_f16(a0, vfrag[0][kk],     acc[0], 0, 0, 0);
            acc[1] = __builtin_amdgcn_mfma_f32_16x16x32_f16(a0, vfrag[1][kk],     acc[1], 0, 0, 0);
            acc[2] = __builtin_amdgcn_mfma_f32_16x16x32_f16(a0, vfrag[2][kk],     acc[2], 0, 0, 0);
            acc[3] = __builtin_amdgcn_mfma_f32_16x16x32_f16(a0, vfrag[3][kk],     acc[3], 0, 0, 0);
            acq[0] = __builtin_amdgcn_mfma_f32_16x16x32_f16(a1, vfrag[0][4 + kk], acq[0], 0, 0, 0);
            acq[1] = __builtin_amdgcn_mfma_f32_16x16x32_f16(a1, vfrag[1][4 + kk], acq[1], 0, 0, 0);
            acq[2] = __builtin_amdgcn_mfma_f32_16x16x32_f16(a1, vfrag[2][4 + kk], acq[2], 0, 0, 0);
            acq[3] = __builtin_amdgcn_mfma_f32_16x16x32_f16(a1, vfrag[3][4 + kk], acq[3], 0, 0, 0);
        }

        // ---- K-reduction across the wave pair (lane-contiguous b128) ----
        const int p = ug * 64 + l;        // pair-space slot 0..127
        f4 tot[4];
#pragma unroll
        for (int g = 0; g < 4; ++g) {
            tot[g] = acc[g] + acq[g];
            ldsP[(khalf * 4 + g) * 128 + p] = tot[g];
        }
        LBAR();   // reduction barrier
#pragma unroll
        for (int g = 0; g < 4; ++g)
            tot[g] = tot[g] + ldsP[((khalf ^ 1) * 4 + g) * 128 + p];

        // ---- elementwise for this wave's 2 rows (d = khalf*2 + di) ----
        const unsigned ptag = (unsigned)(t & 1023);
        const int d0 = khalf * 2;
        unsigned pub2[2];
#pragma unroll
        for (int di = 0; di < 2; ++di) {
            const int d = d0 + di;
            const float iv = sigm(tot[0][d]);
            const float fv = sigm(tot[1][d]);
            const float gv = tanh_a(tot[2][d]);
            const float ov = sigm(tot[3][d]);
            const float c = fv * cst2[di] + iv * gv;
            cst2[di] = c;
            const float hv = ov * tanh_a(c);
            pub2[di] = (__float_as_uint(hv) & 0xFFFFFC00u) | ptag;
        }
        if (hi < 2) {
            unsigned* hw = hbuf + (size_t)((pb * 8 + ig) * 8 + hi * 4 + d0) * 512 + unit;
            asm volatile(
                "global_store_dword %2, %0, off sc0 sc1\n\t"
                "global_store_dword %2, %1, off offset:2048 sc0 sc1"
                :: "v"(pub2[0]), "v"(pub2[1]), "v"(hw)
                : "memory");
        }
    }
}

// ---------------- k_fc: out[b] = h_last[b,:] . fc_w + fc_b ----------------
__global__ __launch_bounds__(64) void k_fc(
    const unsigned* __restrict__ hbuf, const float* __restrict__ fcw,
    const float* __restrict__ fcb, float* __restrict__ out)
{
    const int b = blockIdx.x, l = threadIdx.x;
    // h_1023 lives at parity 1; ig = b>>3, row = b&7; mask the tag bits
    const unsigned* h = hbuf + (size_t)((8 + (b >> 3)) * 8 + (b & 7)) * 512;
    float s = 0.f;
#pragma unroll
    for (int k = 0; k < 8; ++k) {
        const float hv = __uint_as_float(h[l + k * 64] & 0xFFFFFC00u);
        s += hv * fcw[l + k * 64];
    }
    for (int off = 32; off > 0; off >>= 1) s += __shfl_down(s, off, 64);
    if (l == 0) out[b] = s + fcb[0];
}

__global__ __launch_bounds__(64) void k_sentinel(float* out)
{
    out[threadIdx.x] = -777777.0f;   // signature: ws_size too small
}

extern "C" void kernel_launch(void* const* d_in, const int* in_sizes, int n_in,
                              void* d_out, int out_size, void* d_ws, size_t ws_size,
                              hipStream_t stream)
{
    const float* x   = (const float*)d_in[0];
    const float* Ui  = (const float*)d_in[1];
    const float* Vi  = (const float*)d_in[2];
    const float* bi  = (const float*)d_in[3];
    const float* Uf  = (const float*)d_in[4];
    const float* Vf  = (const float*)d_in[5];
    const float* bf  = (const float*)d_in[6];
    const float* Uh  = (const float*)d_in[7];
    const float* Vh  = (const float*)d_in[8];
    const float* bh  = (const float*)d_in[9];
    const float* Uo  = (const float*)d_in[10];
    const float* Vo  = (const float*)d_in[11];
    const float* bo  = (const float*)d_in[12];
    const float* fcw = (const float*)d_in[13];
    const float* fcb = (const float*)d_in[14];
    float* out = (float*)d_out;

    if (ws_size < WS_NEEDED) {
        k_sentinel<<<1, 64, 0, stream>>>(out);
        return;
    }

    unsigned* hbuf = (unsigned*)d_ws;

    k_init<<<256, 256, 0, stream>>>(hbuf);
    k_rec <<<128, 256, 0, stream>>>(x, Ui, Vi, bi, Uf, Vf, bf, Uh, Vh, bh,
                                    Uo, Vo, bo, hbuf);
    k_fc  <<<64,   64, 0, stream>>>(hbuf, fcw, fcb, out);
}